// Round 24
// baseline (204.997 us; speedup 1.0000x reference)
//
#include <hip/hip_runtime.h>
#include <cstdint>
#include <cstddef>

#define DEV __device__ __forceinline__

typedef __attribute__((ext_vector_type(8))) __bf16 bf16x8;
typedef __attribute__((ext_vector_type(4))) float f32x4;

typedef const __attribute__((address_space(1))) void gld_gv;
typedef __attribute__((address_space(3))) void gld_sv;

static constexpr int SEQ = 2048, BAT = 2, DM = 1024, DFF = 4096;
static constexpr int MT = BAT * SEQ;  // 4096 rows total
static constexpr float LOG2E = 1.44269504088896340736f;
static constexpr float SM_SHIFT = 16.0f;  // fixed softmax shift (log2 domain)

struct TrueC  { static constexpr bool value = true;  };
struct FalseC { static constexpr bool value = false; };

DEV unsigned short f2bf_bits(float f) {
    uint32_t u = __builtin_bit_cast(uint32_t, f);
    return (unsigned short)((u + 0x7FFFu + ((u >> 16) & 1u)) >> 16);
}

DEV float bf2f(unsigned short b) {
    return __builtin_bit_cast(float, (uint32_t)b << 16);
}

DEV void gload16(const void* g, void* s) {
    __builtin_amdgcn_global_load_lds((gld_gv*)g, (gld_sv*)s, 16, 0, 0);
}

// fast 2^st -> bf16 bits (st < 0, fixed-shift domain). Int-construction:
// (int)(st*2^23 + 127*2^23) bitcast is 2^st with <=6% mantissa chord error;
// >>16 truncates to bf16. Masked st=-1e30 saturates cvt to INT_MIN ->
// 0x8000 = -0.0 bf16 -> P contributes exactly 0 to PV and l.
DEV unsigned short fast_exp2_bf(float st) {
    const int i = (int)fmaf(st, 8388608.0f, 1065353216.0f);
    return (unsigned short)((unsigned)i >> 16);
}

// ---------------- fused: weight transposes (+scale) AND LayerNorm-1 --------
// One launch for ALL input-only work: blocks 0..3071 transpose/convert the six
// weights (64x64 tiles); blocks 3072..7167 run LN1 on row (id-3072).
__global__ __launch_bounds__(256) void prep_all(
    const float* __restrict__ Wq, const float* __restrict__ Wk,
    const float* __restrict__ Wv, const float* __restrict__ Wo,
    const float* __restrict__ W1, const float* __restrict__ W2,
    unsigned short* __restrict__ WqkT, unsigned short* __restrict__ WvT,
    unsigned short* __restrict__ WoT, unsigned short* __restrict__ W1T,
    unsigned short* __restrict__ W2T,
    const float* __restrict__ x, const float* __restrict__ ln1g,
    const float* __restrict__ ln1b, unsigned short* __restrict__ xn1)
{
    const int id = blockIdx.x;
    const int t = threadIdx.x;

    if (id >= 3072) {   // ---- LayerNorm-1 path (f32 in -> bf16 out)
        const int row = id - 3072;
        const float* xr = x + (size_t)row * DM;
        float4 v = *(const float4*)(xr + t * 4);
        float s = v.x + v.y + v.z + v.w;
        float q = v.x * v.x + v.y * v.y + v.z * v.z + v.w * v.w;
        #pragma unroll
        for (int m = 1; m < 64; m <<= 1) { s += __shfl_xor(s, m); q += __shfl_xor(q, m); }
        __shared__ float red[8];
        const int w = t >> 6;
        if ((t & 63) == 0) { red[w] = s; red[4 + w] = q; }
        __syncthreads();
        s = red[0] + red[1] + red[2] + red[3];
        q = red[4] + red[5] + red[6] + red[7];
        const float mu = s * (1.0f / DM);
        const float rstd = rsqrtf(q * (1.0f / DM) - mu * mu + 1e-5f);
        float4 g4 = *(const float4*)(ln1g + t * 4);
        float4 b4 = *(const float4*)(ln1b + t * 4);
        short4 o;
        o.x = (short)f2bf_bits((v.x - mu) * rstd * g4.x + b4.x);
        o.y = (short)f2bf_bits((v.y - mu) * rstd * g4.y + b4.y);
        o.z = (short)f2bf_bits((v.z - mu) * rstd * g4.z + b4.z);
        o.w = (short)f2bf_bits((v.w - mu) * rstd * g4.w + b4.w);
        *(short4*)(xn1 + (size_t)row * DM + t * 4) = o;
        return;
    }

    // ---- weight transpose path
    const float* W; unsigned short* WT; int K, N, k0, n0; float scale = 1.0f;
    if (id < 256)       { int loc = id;        W = Wq; WT = WqkT;             K = 1024; N = 1024; k0 = (loc & 15) * 64; n0 = (loc >> 4) * 64; scale = 0.125f * LOG2E; }
    else if (id < 512)  { int loc = id - 256;  W = Wk; WT = WqkT + 1024*1024; K = 1024; N = 1024; k0 = (loc & 15) * 64; n0 = (loc >> 4) * 64; }
    else if (id < 768)  { int loc = id - 512;  W = Wv; WT = WvT;              K = 1024; N = 1024; k0 = (loc & 15) * 64; n0 = (loc >> 4) * 64; }
    else if (id < 1024) { int loc = id - 768;  W = Wo; WT = WoT;              K = 1024; N = 1024; k0 = (loc & 15) * 64; n0 = (loc >> 4) * 64; }
    else if (id < 2048) { int loc = id - 1024; W = W1; WT = W1T;              K = 1024; N = 4096; k0 = (loc & 15) * 64; n0 = (loc >> 4) * 64; }
    else                { int loc = id - 2048; W = W2; WT = W2T;              K = 4096; N = 1024; k0 = (loc & 63) * 64; n0 = (loc >> 6) * 64; }

    __shared__ float tile[64][65];
    const int r = t >> 6, c = t & 63;
    #pragma unroll
    for (int p = 0; p < 16; ++p)
        tile[p * 4 + r][c] = W[(size_t)(k0 + p * 4 + r) * N + n0 + c];
    __syncthreads();
    #pragma unroll
    for (int p = 0; p < 16; ++p)
        WT[(size_t)(n0 + p * 4 + r) * K + k0 + c] = f2bf_bits(tile[c][p * 4 + r] * scale);
}

// ---------------- LayerNorm (bf16 in -> bf16 out) ----------------
__global__ __launch_bounds__(256) void ln_kernel_b(const unsigned short* __restrict__ x,
        const float* __restrict__ gw, const float* __restrict__ bw,
        unsigned short* __restrict__ y)
{
    const int row = blockIdx.x, t = threadIdx.x;
    const unsigned short* xr = x + (size_t)row * DM + t * 4;
    ushort4 u = *(const ushort4*)xr;
    float4 v = { bf2f(u.x), bf2f(u.y), bf2f(u.z), bf2f(u.w) };
    float s = v.x + v.y + v.z + v.w;
    float q = v.x * v.x + v.y * v.y + v.z * v.z + v.w * v.w;
    #pragma unroll
    for (int m = 1; m < 64; m <<= 1) { s += __shfl_xor(s, m); q += __shfl_xor(q, m); }
    __shared__ float red[8];
    const int w = t >> 6;
    if ((t & 63) == 0) { red[w] = s; red[4 + w] = q; }
    __syncthreads();
    s = red[0] + red[1] + red[2] + red[3];
    q = red[4] + red[5] + red[6] + red[7];
    const float mu = s * (1.0f / DM);
    const float rstd = rsqrtf(q * (1.0f / DM) - mu * mu + 1e-5f);
    float4 g4 = *(const float4*)(gw + t * 4);
    float4 b4 = *(const float4*)(bw + t * 4);
    short4 o;
    o.x = (short)f2bf_bits((v.x - mu) * rstd * g4.x + b4.x);
    o.y = (short)f2bf_bits((v.y - mu) * rstd * g4.y + b4.y);
    o.z = (short)f2bf_bits((v.z - mu) * rstd * g4.z + b4.z);
    o.w = (short)f2bf_bits((v.w - mu) * rstd * g4.w + b4.w);
    *(short4*)(y + (size_t)row * DM + t * 4) = o;
}

// ---------------- GEMM: depth-2 pipelined, counted vmcnt, swizzled LDS -----
// EPI 0: bf16 out, *scale      1: f32 out + res     2: +bias, GELU, bf16
// EPI 3: +bias +res, f32       4: V producer -> fragment-ordered VTf
// EPI 5: QK producer (N=2048): Q row-major (bn<4) | K fragment-ordered Kf
//        via `bias` (bn 4..7)
// EPI 6: bf16 out + f32 res    7: f32 out + bias + BF16 res
// SWZ 1: XCD-chunked swizzle, 32x8 grid (1-D, 256 blocks)
// SWZ 2: XCD-chunked swizzle, 32x16 grid (1-D, 512 blocks)
template<int EPI, int BM, int BN, int WVM, int WVN, int SWZ = 0>
__global__ __launch_bounds__(WVM * WVN * 64, (BN == 64 ? 3 : 2)) void gemm_pipe(
    const unsigned short* __restrict__ A, const unsigned short* __restrict__ BT,
    void* __restrict__ Cp, const float* __restrict__ bias,
    const float* __restrict__ res, int Nsz, int Ksz, float scale)
{
    constexpr int NT = WVM * WVN * 64;         // threads
    constexpr int TOTCH = (BM + BN) * 8;       // 16B chunks per tile (A|B)
    constexpr int TL = TOTCH / NT;             // gload_lds per thread per tile
    constexpr int MREP = BM / (WVM * 16);
    constexpr int WMR = MREP * 16;             // wave rows
    __shared__ alignas(16) unsigned short lds[2][(BM + BN) * 64];

    const int t = threadIdx.x, l = t & 63, w = t >> 6;
    const int wm = w / WVN, wn = w % WVN;
    const int lr = l & 15, lg = l >> 4;
    int bm, bn;
    if constexpr (SWZ == 1) {   // 32x8 grid, 1-D launch of 256 blocks
        const int i = blockIdx.x;
        const int xcd = i & 7, s = i >> 3;        // s 0..31
        const int c = xcd + 8 * (s >> 4);         // chunk 0..15 (8 x 2)
        const int j = s & 15;                     // within 4x4 chunk
        bm = (c & 7) * 4 + (j & 3);
        bn = (c >> 3) * 4 + (j >> 2);
    } else if constexpr (SWZ == 2) {  // 32x16 grid, 1-D launch of 512 blocks
        const int i = blockIdx.x;
        const int xcd = i & 7, s = i >> 3;        // s 0..63
        const int c = xcd + 8 * (s >> 4);         // chunk 0..31 (8 x 4)
        const int j = s & 15;
        bm = (c & 7) * 4 + (j & 3);
        bn = (c >> 3) * 4 + (j >> 2);
    } else {
        bm = blockIdx.x; bn = blockIdx.y;
    }

    f32x4 acc[MREP][4] = {};

    const int nk = Ksz / 64;

    auto STAGE = [&](int tile, char* slot) {
        const int k0 = tile * 64;
        #pragma unroll
        for (int p = 0; p < TL; ++p) {
            const int ci = t + p * NT;
            const bool isA = ci < BM * 8;
            const int rr = (isA ? ci : ci - BM * 8) >> 3;
            const int cc = ci & 7;
            const unsigned short* srow = isA
                ? A + (size_t)(bm * BM + rr) * Ksz
                : BT + (size_t)(bn * BN + rr) * Ksz;
            gload16(srow + k0 + ((cc ^ (rr & 7)) << 3), slot + ci * 16);
        }
    };

    STAGE(0, (char*)lds[0]);
    STAGE(1, (char*)lds[1]);

    for (int kt = 0; kt < nk; ++kt) {
        char* slot = (char*)lds[kt & 1];
        const char* la = slot;
        const char* lb = slot + BM * 128;
        if (kt + 1 < nk) {  // tile kt+1 still in flight: counted wait
            if constexpr (TL == 8)      asm volatile("s_waitcnt vmcnt(8)" ::: "memory");
            else if constexpr (TL == 6) asm volatile("s_waitcnt vmcnt(6)" ::: "memory");
            else                        asm volatile("s_waitcnt vmcnt(3)" ::: "memory");
        } else {            // last tile: nothing behind it -- full drain
            asm volatile("s_waitcnt vmcnt(0)" ::: "memory");
        }
        __builtin_amdgcn_s_barrier();
        __builtin_amdgcn_sched_barrier(0);

        __builtin_amdgcn_s_setprio(1);
        #pragma unroll
        for (int ks = 0; ks < 2; ++ks) {
            bf16x8 af[MREP], bfr[4];
            #pragma unroll
            for (int i = 0; i < MREP; ++i) {
                const int ra = wm * WMR + i * 16 + lr;
                af[i] = *(const bf16x8*)(la + (ra * 8 + ((ks * 4 + lg) ^ (ra & 7))) * 16);
            }
            #pragma unroll
            for (int i = 0; i < 4; ++i) {
                const int rb_ = wn * 64 + i * 16 + lr;
                bfr[i] = *(const bf16x8*)(lb + (rb_ * 8 + ((ks * 4 + lg) ^ (rb_ & 7))) * 16);
            }
            #pragma unroll
            for (int mb = 0; mb < MREP; ++mb)
                #pragma unroll
                for (int nb = 0; nb < 4; ++nb) {
                    if (EPI == 4)  // swapped operands -> transposed output tile
                        acc[mb][nb] = __builtin_amdgcn_mfma_f32_16x16x32_bf16(
                            bfr[nb], af[mb], acc[mb][nb], 0, 0, 0);
                    else
                        acc[mb][nb] = __builtin_amdgcn_mfma_f32_16x16x32_bf16(
                            af[mb], bfr[nb], acc[mb][nb], 0, 0, 0);
                }
        }
        __builtin_amdgcn_s_setprio(0);
        __builtin_amdgcn_s_barrier();
        if (kt + 2 < nk) STAGE(kt + 2, slot);
    }

    const int rb = bm * BM + wm * WMR, cb = bn * BN + wn * 64;
    #pragma unroll
    for (int mb = 0; mb < MREP; ++mb)
        #pragma unroll
        for (int nb = 0; nb < 4; ++nb)
            #pragma unroll
            for (int r = 0; r < 4; ++r) {
                float v = acc[mb][nb][r];
                if (EPI == 4) {
                    // fragment-ordered V: D rows = features, D cols = tokens
                    const int xrow = rb + mb * 16 + lr;          // token
                    const int feat = cb + nb * 16 + lg * 4 + r;  // feature
                    const int bb = xrow >> 11, sl = xrow & (SEQ - 1);
                    const int hh = feat >> 6, n = feat & 63;
                    const int nbf = n >> 4, lrf = n & 15;
                    const int ksg = sl >> 5, lgf = (sl & 15) >> 2;
                    const int half = (sl >> 4) & 1, j = sl & 3;
                    ((unsigned short*)Cp)[((size_t)(bb * 16 + hh) * 256 + ksg * 4 + nbf) * 512
                        + (lgf * 16 + lrf) * 8 + half * 4 + j] = f2bf_bits(v);
                    continue;
                }
                const int row = rb + mb * 16 + lg * 4 + r;
                const int col = cb + nb * 16 + lr;
                if (EPI == 5) {
                    const int bb = row >> 11, sl = row & (SEQ - 1);
                    if (col < 1024) {        // Q: row-major [MT][1024]
                        ((unsigned short*)Cp)[(size_t)row * 1024 + col] = f2bf_bits(v);
                    } else {                 // K: fragment-ordered Kf
                        const int hh = (col >> 6) & 15, d = col & 63;
                        const int ktf = sl >> 7, mbf = (sl & 127) >> 4, lrf = sl & 15;
                        const int ksf = d >> 5, lgf = (d & 31) >> 3, j2 = d & 7;
                        unsigned short* Kf = (unsigned short*)(uintptr_t)bias;
                        Kf[((((size_t)(bb * 16 + hh) * 16 + ktf) * 8 + mbf) * 2 + ksf) * 512
                           + (lgf * 16 + lrf) * 8 + j2] = f2bf_bits(v);
                    }
                    continue;
                }
                const size_t idx = (size_t)row * Nsz + col;
                if (EPI == 0) {
                    ((unsigned short*)Cp)[idx] = f2bf_bits(v * scale);
                } else if (EPI == 1) {
                    ((float*)Cp)[idx] = v + res[idx];
                } else if (EPI == 2) {
                    // tanh-GELU in sigmoid form: x*sigmoid(1.59577x(1+0.044715x^2))
                    const float xx = v + bias[col];
                    const float tq = xx * xx;
                    const float u = xx * fmaf(tq, 0.044715f, 1.0f);
                    const float e = exp2f(u * -2.30220795f);
                    ((unsigned short*)Cp)[idx] =
                        f2bf_bits(xx * __builtin_amdgcn_rcpf(1.0f + e));
                } else if (EPI == 6) {
                    ((unsigned short*)Cp)[idx] = f2bf_bits(v + res[idx]);
                } else if (EPI == 7) {
                    const float rv = bf2f(((const unsigned short*)res)[idx]);
                    ((float*)Cp)[idx] = v + bias[col] + rv;
                } else {
                    ((float*)Cp)[idx] = v + bias[col] + res[idx];
                }
            }
}

// ---------------- causal flash attention (XCD-L2 swizzle + fast-exp2) ------
// (unchanged from R18..R23)
__global__ __launch_bounds__(512, 2) void attn_kernel(
    const unsigned short* __restrict__ Qg, const unsigned short* __restrict__ Kfg,
    const unsigned short* __restrict__ Vfg, unsigned short* __restrict__ Og)
{
    __shared__ alignas(16) unsigned short ldsK[2][128 * 64];
    __shared__ alignas(16) unsigned short ldsVT[2][64 * 128];
    const int t = threadIdx.x, l = t & 63, w = t >> 6;
    const int lr = l & 15, lg = l >> 4;
    const int i = blockIdx.x;
    const int qtA = (i >> 3) & 7, qtB = 15 - qtA;
    const int bh = (i & 7) + 8 * (i >> 6);
    const int b = bh >> 4, h = bh & 15;
    const unsigned short* Qbase = Qg + (size_t)b * SEQ * 1024 + h * 64;
    const unsigned short* Kbase = Kfg + (size_t)bh * 131072;
    const unsigned short* Vbase = Vfg + (size_t)bh * 131072;

    const int wq0A = qtA * 128 + w * 16, qrowA = wq0A + lr;
    const int wq0B = qtB * 128 + w * 16, qrowB = wq0B + lr;
    bf16x8 qfA[2], qfB[2];
    #pragma unroll
    for (int ks = 0; ks < 2; ++ks) {
        qfA[ks] = *(const bf16x8*)(Qbase + (size_t)qrowA * 1024 + ks * 32 + lg * 8);
        qfB[ks] = *(const bf16x8*)(Qbase + (size_t)qrowB * 1024 + ks * 32 + lg * 8);
    }

    f32x4 oaccA[4] = {}, oaccB[4] = {};
    f32x4 laccA = {}, laccB = {};
    bf16x8 onesv;
    #pragma unroll
    for (int i2 = 0; i2 < 8; ++i2) onesv[i2] = (__bf16)1.0f;

    const int lby = l * 16;  // lane byte offset for fragment reads
    const int nkt = qtB + 1;

    // prologue: stage tile 0 (pure linear copy)
    #pragma unroll
    for (int p = 0; p < 2; ++p) {
        const int ci = t + p * 512;
        gload16(Kbase + (size_t)ci * 8, (char*)ldsK[0] + ci * 16);
        gload16(Vbase + (size_t)ci * 8, (char*)ldsVT[0] + ci * 16);
    }
    asm volatile("s_waitcnt vmcnt(0)" ::: "memory");
    __builtin_amdgcn_s_barrier();

    for (int kt = 0; kt < nkt; ++kt) {
        const int cur = kt & 1;
        if (kt + 1 < nkt) {
            #pragma unroll
            for (int p = 0; p < 2; ++p) {
                const int ci = t + p * 512;
                gload16(Kbase + (size_t)((kt + 1) * 1024 + ci) * 8,
                        (char*)ldsK[cur ^ 1] + ci * 16);
                gload16(Vbase + (size_t)((kt + 1) * 1024 + ci) * 8,
                        (char*)ldsVT[cur ^ 1] + ci * 16);
            }
            asm volatile("s_waitcnt vmcnt(4)" ::: "memory");
        } else {
            asm volatile("s_waitcnt vmcnt(0)" ::: "memory");
        }
        __builtin_amdgcn_s_barrier();
        __builtin_amdgcn_sched_barrier(0);

        const char* lk = (const char*)ldsK[cur];
        const char* lv = (const char*)ldsVT[cur];
        const int kt0 = kt * 128;

        // mask + P = fast-exp2(st) directly in bf16 + pack
        auto run_softmax = [&](f32x4 (&st)[8], int qrow, bool diag, bf16x8 (&pa)[4]) {
            if (diag) {
                #pragma unroll
                for (int mb = 0; mb < 8; ++mb)
                    #pragma unroll
                    for (int r = 0; r < 4; ++r)
                        if (kt0 + mb * 16 + lg * 4 + r > qrow) st[mb][r] = -1e30f;
            }
            union { bf16x8 v; unsigned short u[8]; } pk[4];
            #pragma unroll
            for (int ks = 0; ks < 4; ++ks)
                #pragma unroll
                for (int jj = 0; jj < 4; ++jj) {
                    pk[ks].u[jj]     = fast_exp2_bf(st[2 * ks][jj]);
                    pk[ks].u[jj + 4] = fast_exp2_bf(st[2 * ks + 1][jj]);
                }
            #pragma unroll
            for (int ks = 0; ks < 4; ++ks) pa[ks] = pk[ks].v;
        };

        auto iter_body = [&](auto DOA) {
            constexpr bool doA = DOA.value;
            f32x4 stA[8], stB[8];
            #pragma unroll
            for (int mb = 0; mb < 8; ++mb)
                #pragma unroll
                for (int r = 0; r < 4; ++r) { stA[mb][r] = -SM_SHIFT; stB[mb][r] = -SM_SHIFT; }
            // QK off one K-frag read: chunk (mb*2+ks)*64 + lane (const offsets)
            __builtin_amdgcn_s_setprio(1);
            #pragma unroll
            for (int ks = 0; ks < 2; ++ks)
                #pragma unroll
                for (int mb = 0; mb < 8; ++mb) {
                    bf16x8 kf = *(const bf16x8*)(lk + (mb * 2 + ks) * 1024 + lby);
                    if constexpr (doA)
                        stA[mb] = __builtin_amdgcn_mfma_f32_16x16x32_bf16(kf, qfA[ks], stA[mb], 0, 0, 0);
                    stB[mb] = __builtin_amdgcn_mfma_f32_16x16x32_bf16(kf, qfB[ks], stB[mb], 0, 0, 0);
                }
            __builtin_amdgcn_s_setprio(0);

            bf16x8 paA[4], paB[4];
            if constexpr (doA)
                run_softmax(stA, qrowA, kt == qtA, paA);
            run_softmax(stB, qrowB, kt == qtB, paB);

            // PV off one V-frag read: chunk (ks*4+nb)*64 + lane
            __builtin_amdgcn_s_setprio(1);
            #pragma unroll
            for (int ks = 0; ks < 4; ++ks) {
                #pragma unroll
                for (int nb = 0; nb < 4; ++nb) {
                    bf16x8 vbv = *(const bf16x8*)(lv + (ks * 4 + nb) * 1024 + lby);
                    if constexpr (doA)
                        oaccA[nb] = __builtin_amdgcn_mfma_f32_16x16x32_bf16(paA[ks], vbv, oaccA[nb], 0, 0, 0);
                    oaccB[nb] = __builtin_amdgcn_mfma_f32_16x16x32_bf16(paB[ks], vbv, oaccB[nb], 0, 0, 0);
                }
                if constexpr (doA)
                    laccA = __builtin_amdgcn_mfma_f32_16x16x32_bf16(paA[ks], onesv, laccA, 0, 0, 0);
                laccB = __builtin_amdgcn_mfma_f32_16x16x32_bf16(paB[ks], onesv, laccB, 0, 0, 0);
            }
            __builtin_amdgcn_s_setprio(0);
        };

        if (kt <= qtA) iter_body(TrueC{}); else iter_body(FalseC{});

        __builtin_amdgcn_s_barrier();
    }

    unsigned short* Obase = Og + (size_t)b * SEQ * DM + h * 64;
    #pragma unroll
    for (int j = 0; j < 4; ++j) {
        const float invA = 1.0f / laccA[j];
        const float invB = 1.0f / laccB[j];
        const int rowA = wq0A + lg * 4 + j;
        const int rowB = wq0B + lg * 4 + j;
        #pragma unroll
        for (int nb = 0; nb < 4; ++nb) {
            Obase[(size_t)rowA * DM + nb * 16 + lr] = f2bf_bits(oaccA[nb][j] * invA);
            Obase[(size_t)rowB * DM + nb * 16 + lr] = f2bf_bits(oaccB[nb][j] * invB);
        }
    }
}

// ---------------- launcher ----------------
extern "C" void kernel_launch(void* const* d_in, const int* in_sizes, int n_in,
                              void* d_out, int out_size, void* d_ws, size_t ws_size,
                              hipStream_t stream) {
    (void)in_sizes; (void)n_in; (void)out_size; (void)ws_size;
    const float* x    = (const float*)d_in[0];
    const float* Wq   = (const float*)d_in[1];
    const float* Wk   = (const float*)d_in[2];
    const float* Wv   = (const float*)d_in[3];
    const float* Wo   = (const float*)d_in[4];
    const float* ln1g = (const float*)d_in[5];
    const float* ln1b = (const float*)d_in[6];
    const float* ln2g = (const float*)d_in[7];
    const float* ln2b = (const float*)d_in[8];
    const float* W1   = (const float*)d_in[9];
    const float* b1   = (const float*)d_in[10];
    const float* W2   = (const float*)d_in[11];
    const float* b2   = (const float*)d_in[12];
    float* out = (float*)d_out;

    char* ws = (char*)d_ws;
    const size_t MB = 1ull << 20;
    unsigned short* xn1   = (unsigned short*)(ws + 0 * MB);   // 8 MB [4096][1024]
    unsigned short* Qb    = (unsigned short*)(ws + 8 * MB);   // 8 MB [4096][1024]
    unsigned short* Kf    = (unsigned short*)(ws + 16 * MB);  // 8 MB fragment-ordered
    unsigned short* Vf    = (unsigned short*)(ws + 24 * MB);  // 8 MB fragment-ordered
    unsigned short* ffa   = (unsigned short*)(ws + 0 * MB);   // 32 MB (aliases the above)
    unsigned short* attno = (unsigned short*)(ws + 32 * MB);  // 8 MB
    unsigned short* x2b   = (unsigned short*)(ws + 40 * MB);  // 8 MB bf16 residual
    unsigned short* h2    = (unsigned short*)(ws + 56 * MB);  // 8 MB
    unsigned short* WqkT  = (unsigned short*)(ws + 64 * MB);  // 4 MB [2048][1024]
    unsigned short* WvT   = (unsigned short*)(ws + 68 * MB);  // 2 MB
    unsigned short* WoT   = (unsigned short*)(ws + 70 * MB);  // 2 MB
    unsigned short* W1T   = (unsigned short*)(ws + 72 * MB);  // 8 MB
    unsigned short* W2T   = (unsigned short*)(ws + 80 * MB);  // 8 MB  (total 88 MB)

    dim3 blk(256);
    // ALL input-only prep (six weight transposes + LN1) in ONE launch
    prep_all<<<dim3(3072 + MT), blk, 0, stream>>>(Wq, Wk, Wv, Wo, W1, W2,
                                                  WqkT, WvT, WoT, W1T, W2T,
                                                  x, ln1g, ln1b, xn1);

    // fused Q|K projection (XCD-chunked swizzle): Q -> Qb, K -> Kf
    gemm_pipe<5, 128, 256, 2, 4, 1><<<dim3(256), dim3(512), 0, stream>>>(
        xn1, WqkT, Qb, (const float*)Kf, nullptr, 2048, DM, 1.0f);
    // V projection -> Vf fragment-ordered; XCD-chunked swizzle (SWZ=2)
    gemm_pipe<4, 128, 64, 4, 1, 2><<<dim3(512), blk, 0, stream>>>(
        xn1, WvT, Vf, nullptr, nullptr, DM, DM, 1.0f);

    attn_kernel<<<dim3(256), dim3(512), 0, stream>>>(Qb, Kf, Vf, attno);

    // Wo + residual -> bf16 x2b; XCD-chunked swizzle (SWZ=2)
    gemm_pipe<6, 128, 64, 4, 1, 2><<<dim3(512), blk, 0, stream>>>(
        attno, WoT, x2b, nullptr, x, DM, DM, 1.0f);

    ln_kernel_b<<<dim3(MT), blk, 0, stream>>>(x2b, ln2g, ln2b, h2);

    // FF1: transplanted QK structure (128x256, 8 waves) -- the measured-best
    // GEMM schedule in this pipeline (~860 TF) -- with fast GELU epilogue.
    // Grid 512 x 512 thr, XCD-chunked swizzle (SWZ=2).
    gemm_pipe<2, 128, 256, 2, 4, 2><<<dim3(512), dim3(512), 0, stream>>>(
        h2, W1T, ffa, b1, nullptr, DFF, DM, 1.0f);
    // FF2 + bias + bf16 residual -> f32 out; XCD-chunked swizzle (SWZ=2)
    gemm_pipe<7, 128, 64, 4, 1, 2><<<dim3(512), blk, 0, stream>>>(
        ffa, W2T, out, b2, (const float*)x2b, DM, DFF, 1.0f);
}

// Round 25
// 197.208 us; speedup vs baseline: 1.0395x; 1.0395x over previous
//
#include <hip/hip_runtime.h>
#include <cstdint>
#include <cstddef>

#define DEV __device__ __forceinline__

typedef __attribute__((ext_vector_type(8))) __bf16 bf16x8;
typedef __attribute__((ext_vector_type(4))) float f32x4;

typedef const __attribute__((address_space(1))) void gld_gv;
typedef __attribute__((address_space(3))) void gld_sv;

static constexpr int SEQ = 2048, BAT = 2, DM = 1024, DFF = 4096;
static constexpr int MT = BAT * SEQ;  // 4096 rows total
static constexpr float LOG2E = 1.44269504088896340736f;
static constexpr float SM_SHIFT = 16.0f;  // fixed softmax shift (log2 domain)

struct TrueC  { static constexpr bool value = true;  };
struct FalseC { static constexpr bool value = false; };

DEV unsigned short f2bf_bits(float f) {
    uint32_t u = __builtin_bit_cast(uint32_t, f);
    return (unsigned short)((u + 0x7FFFu + ((u >> 16) & 1u)) >> 16);
}

DEV float bf2f(unsigned short b) {
    return __builtin_bit_cast(float, (uint32_t)b << 16);
}

DEV void gload16(const void* g, void* s) {
    __builtin_amdgcn_global_load_lds((gld_gv*)g, (gld_sv*)s, 16, 0, 0);
}

// fast 2^st -> bf16 bits (st < 0, fixed-shift domain). Int-construction:
// (int)(st*2^23 + 127*2^23) bitcast is 2^st with <=6% mantissa chord error;
// >>16 truncates to bf16. Masked st=-1e30 saturates cvt to INT_MIN ->
// 0x8000 = -0.0 bf16 -> P contributes exactly 0 to PV and l.
DEV unsigned short fast_exp2_bf(float st) {
    const int i = (int)fmaf(st, 8388608.0f, 1065353216.0f);
    return (unsigned short)((unsigned)i >> 16);
}

// ---------------- fused: weight transposes (+scale) AND LayerNorm-1 --------
// One launch for ALL input-only work: blocks 0..3071 transpose/convert the six
// weights (64x64 tiles); blocks 3072..7167 run LN1 on row (id-3072).
__global__ __launch_bounds__(256) void prep_all(
    const float* __restrict__ Wq, const float* __restrict__ Wk,
    const float* __restrict__ Wv, const float* __restrict__ Wo,
    const float* __restrict__ W1, const float* __restrict__ W2,
    unsigned short* __restrict__ WqkT, unsigned short* __restrict__ WvT,
    unsigned short* __restrict__ WoT, unsigned short* __restrict__ W1T,
    unsigned short* __restrict__ W2T,
    const float* __restrict__ x, const float* __restrict__ ln1g,
    const float* __restrict__ ln1b, unsigned short* __restrict__ xn1)
{
    const int id = blockIdx.x;
    const int t = threadIdx.x;

    if (id >= 3072) {   // ---- LayerNorm-1 path (f32 in -> bf16 out)
        const int row = id - 3072;
        const float* xr = x + (size_t)row * DM;
        float4 v = *(const float4*)(xr + t * 4);
        float s = v.x + v.y + v.z + v.w;
        float q = v.x * v.x + v.y * v.y + v.z * v.z + v.w * v.w;
        #pragma unroll
        for (int m = 1; m < 64; m <<= 1) { s += __shfl_xor(s, m); q += __shfl_xor(q, m); }
        __shared__ float red[8];
        const int w = t >> 6;
        if ((t & 63) == 0) { red[w] = s; red[4 + w] = q; }
        __syncthreads();
        s = red[0] + red[1] + red[2] + red[3];
        q = red[4] + red[5] + red[6] + red[7];
        const float mu = s * (1.0f / DM);
        const float rstd = rsqrtf(q * (1.0f / DM) - mu * mu + 1e-5f);
        float4 g4 = *(const float4*)(ln1g + t * 4);
        float4 b4 = *(const float4*)(ln1b + t * 4);
        short4 o;
        o.x = (short)f2bf_bits((v.x - mu) * rstd * g4.x + b4.x);
        o.y = (short)f2bf_bits((v.y - mu) * rstd * g4.y + b4.y);
        o.z = (short)f2bf_bits((v.z - mu) * rstd * g4.z + b4.z);
        o.w = (short)f2bf_bits((v.w - mu) * rstd * g4.w + b4.w);
        *(short4*)(xn1 + (size_t)row * DM + t * 4) = o;
        return;
    }

    // ---- weight transpose path
    const float* W; unsigned short* WT; int K, N, k0, n0; float scale = 1.0f;
    if (id < 256)       { int loc = id;        W = Wq; WT = WqkT;             K = 1024; N = 1024; k0 = (loc & 15) * 64; n0 = (loc >> 4) * 64; scale = 0.125f * LOG2E; }
    else if (id < 512)  { int loc = id - 256;  W = Wk; WT = WqkT + 1024*1024; K = 1024; N = 1024; k0 = (loc & 15) * 64; n0 = (loc >> 4) * 64; }
    else if (id < 768)  { int loc = id - 512;  W = Wv; WT = WvT;              K = 1024; N = 1024; k0 = (loc & 15) * 64; n0 = (loc >> 4) * 64; }
    else if (id < 1024) { int loc = id - 768;  W = Wo; WT = WoT;              K = 1024; N = 1024; k0 = (loc & 15) * 64; n0 = (loc >> 4) * 64; }
    else if (id < 2048) { int loc = id - 1024; W = W1; WT = W1T;              K = 1024; N = 4096; k0 = (loc & 15) * 64; n0 = (loc >> 4) * 64; }
    else                { int loc = id - 2048; W = W2; WT = W2T;              K = 4096; N = 1024; k0 = (loc & 63) * 64; n0 = (loc >> 6) * 64; }

    __shared__ float tile[64][65];
    const int r = t >> 6, c = t & 63;
    #pragma unroll
    for (int p = 0; p < 16; ++p)
        tile[p * 4 + r][c] = W[(size_t)(k0 + p * 4 + r) * N + n0 + c];
    __syncthreads();
    #pragma unroll
    for (int p = 0; p < 16; ++p)
        WT[(size_t)(n0 + p * 4 + r) * K + k0 + c] = f2bf_bits(tile[c][p * 4 + r] * scale);
}

// ---------------- LayerNorm (bf16 in -> bf16 out) ----------------
__global__ __launch_bounds__(256) void ln_kernel_b(const unsigned short* __restrict__ x,
        const float* __restrict__ gw, const float* __restrict__ bw,
        unsigned short* __restrict__ y)
{
    const int row = blockIdx.x, t = threadIdx.x;
    const unsigned short* xr = x + (size_t)row * DM + t * 4;
    ushort4 u = *(const ushort4*)xr;
    float4 v = { bf2f(u.x), bf2f(u.y), bf2f(u.z), bf2f(u.w) };
    float s = v.x + v.y + v.z + v.w;
    float q = v.x * v.x + v.y * v.y + v.z * v.z + v.w * v.w;
    #pragma unroll
    for (int m = 1; m < 64; m <<= 1) { s += __shfl_xor(s, m); q += __shfl_xor(q, m); }
    __shared__ float red[8];
    const int w = t >> 6;
    if ((t & 63) == 0) { red[w] = s; red[4 + w] = q; }
    __syncthreads();
    s = red[0] + red[1] + red[2] + red[3];
    q = red[4] + red[5] + red[6] + red[7];
    const float mu = s * (1.0f / DM);
    const float rstd = rsqrtf(q * (1.0f / DM) - mu * mu + 1e-5f);
    float4 g4 = *(const float4*)(gw + t * 4);
    float4 b4 = *(const float4*)(bw + t * 4);
    short4 o;
    o.x = (short)f2bf_bits((v.x - mu) * rstd * g4.x + b4.x);
    o.y = (short)f2bf_bits((v.y - mu) * rstd * g4.y + b4.y);
    o.z = (short)f2bf_bits((v.z - mu) * rstd * g4.z + b4.z);
    o.w = (short)f2bf_bits((v.w - mu) * rstd * g4.w + b4.w);
    *(short4*)(y + (size_t)row * DM + t * 4) = o;
}

// ---------------- GEMM: depth-2 pipelined, counted vmcnt, swizzled LDS -----
// EPI 0: bf16 out, *scale      1: f32 out + res     2: +bias, GELU, bf16
// EPI 3: +bias +res, f32       4: V producer -> fragment-ordered VTf
// EPI 5: QK producer (N=2048): Q row-major (bn<4) | K fragment-ordered Kf
//        via `bias` (bn 4..7)
// EPI 6: bf16 out + f32 res    7: f32 out + bias + BF16 res
// SWZ 1: XCD-chunked swizzle, 32x8 grid (1-D, 256 blocks)
// SWZ 2: XCD-chunked swizzle, 32x16 grid (1-D, 512 blocks)
template<int EPI, int BM, int BN, int WVM, int WVN, int SWZ = 0>
__global__ __launch_bounds__(WVM * WVN * 64, (BN == 64 ? 3 : 2)) void gemm_pipe(
    const unsigned short* __restrict__ A, const unsigned short* __restrict__ BT,
    void* __restrict__ Cp, const float* __restrict__ bias,
    const float* __restrict__ res, int Nsz, int Ksz, float scale)
{
    constexpr int NT = WVM * WVN * 64;         // threads
    constexpr int TOTCH = (BM + BN) * 8;       // 16B chunks per tile (A|B)
    constexpr int TL = TOTCH / NT;             // gload_lds per thread per tile
    constexpr int MREP = BM / (WVM * 16);
    constexpr int WMR = MREP * 16;             // wave rows
    __shared__ alignas(16) unsigned short lds[2][(BM + BN) * 64];

    const int t = threadIdx.x, l = t & 63, w = t >> 6;
    const int wm = w / WVN, wn = w % WVN;
    const int lr = l & 15, lg = l >> 4;
    int bm, bn;
    if constexpr (SWZ == 1) {   // 32x8 grid, 1-D launch of 256 blocks
        const int i = blockIdx.x;
        const int xcd = i & 7, s = i >> 3;        // s 0..31
        const int c = xcd + 8 * (s >> 4);         // chunk 0..15 (8 x 2)
        const int j = s & 15;                     // within 4x4 chunk
        bm = (c & 7) * 4 + (j & 3);
        bn = (c >> 3) * 4 + (j >> 2);
    } else if constexpr (SWZ == 2) {  // 32x16 grid, 1-D launch of 512 blocks
        const int i = blockIdx.x;
        const int xcd = i & 7, s = i >> 3;        // s 0..63
        const int c = xcd + 8 * (s >> 4);         // chunk 0..31 (8 x 4)
        const int j = s & 15;
        bm = (c & 7) * 4 + (j & 3);
        bn = (c >> 3) * 4 + (j >> 2);
    } else {
        bm = blockIdx.x; bn = blockIdx.y;
    }

    f32x4 acc[MREP][4] = {};

    const int nk = Ksz / 64;

    auto STAGE = [&](int tile, char* slot) {
        const int k0 = tile * 64;
        #pragma unroll
        for (int p = 0; p < TL; ++p) {
            const int ci = t + p * NT;
            const bool isA = ci < BM * 8;
            const int rr = (isA ? ci : ci - BM * 8) >> 3;
            const int cc = ci & 7;
            const unsigned short* srow = isA
                ? A + (size_t)(bm * BM + rr) * Ksz
                : BT + (size_t)(bn * BN + rr) * Ksz;
            gload16(srow + k0 + ((cc ^ (rr & 7)) << 3), slot + ci * 16);
        }
    };

    STAGE(0, (char*)lds[0]);
    STAGE(1, (char*)lds[1]);

    for (int kt = 0; kt < nk; ++kt) {
        char* slot = (char*)lds[kt & 1];
        const char* la = slot;
        const char* lb = slot + BM * 128;
        if (kt + 1 < nk) {  // tile kt+1 still in flight: counted wait
            if constexpr (TL == 8) asm volatile("s_waitcnt vmcnt(8)" ::: "memory");
            else                   asm volatile("s_waitcnt vmcnt(6)" ::: "memory");
        } else {            // last tile: nothing behind it -- full drain
            asm volatile("s_waitcnt vmcnt(0)" ::: "memory");
        }
        __builtin_amdgcn_s_barrier();
        __builtin_amdgcn_sched_barrier(0);

        __builtin_amdgcn_s_setprio(1);
        #pragma unroll
        for (int ks = 0; ks < 2; ++ks) {
            bf16x8 af[MREP], bfr[4];
            #pragma unroll
            for (int i = 0; i < MREP; ++i) {
                const int ra = wm * WMR + i * 16 + lr;
                af[i] = *(const bf16x8*)(la + (ra * 8 + ((ks * 4 + lg) ^ (ra & 7))) * 16);
            }
            #pragma unroll
            for (int i = 0; i < 4; ++i) {
                const int rb_ = wn * 64 + i * 16 + lr;
                bfr[i] = *(const bf16x8*)(lb + (rb_ * 8 + ((ks * 4 + lg) ^ (rb_ & 7))) * 16);
            }
            #pragma unroll
            for (int mb = 0; mb < MREP; ++mb)
                #pragma unroll
                for (int nb = 0; nb < 4; ++nb) {
                    if (EPI == 4)  // swapped operands -> transposed output tile
                        acc[mb][nb] = __builtin_amdgcn_mfma_f32_16x16x32_bf16(
                            bfr[nb], af[mb], acc[mb][nb], 0, 0, 0);
                    else
                        acc[mb][nb] = __builtin_amdgcn_mfma_f32_16x16x32_bf16(
                            af[mb], bfr[nb], acc[mb][nb], 0, 0, 0);
                }
        }
        __builtin_amdgcn_s_setprio(0);
        __builtin_amdgcn_s_barrier();
        if (kt + 2 < nk) STAGE(kt + 2, slot);
    }

    const int rb = bm * BM + wm * WMR, cb = bn * BN + wn * 64;
    #pragma unroll
    for (int mb = 0; mb < MREP; ++mb)
        #pragma unroll
        for (int nb = 0; nb < 4; ++nb)
            #pragma unroll
            for (int r = 0; r < 4; ++r) {
                float v = acc[mb][nb][r];
                if (EPI == 4) {
                    // fragment-ordered V: D rows = features, D cols = tokens
                    const int xrow = rb + mb * 16 + lr;          // token
                    const int feat = cb + nb * 16 + lg * 4 + r;  // feature
                    const int bb = xrow >> 11, sl = xrow & (SEQ - 1);
                    const int hh = feat >> 6, n = feat & 63;
                    const int nbf = n >> 4, lrf = n & 15;
                    const int ksg = sl >> 5, lgf = (sl & 15) >> 2;
                    const int half = (sl >> 4) & 1, j = sl & 3;
                    ((unsigned short*)Cp)[((size_t)(bb * 16 + hh) * 256 + ksg * 4 + nbf) * 512
                        + (lgf * 16 + lrf) * 8 + half * 4 + j] = f2bf_bits(v);
                    continue;
                }
                const int row = rb + mb * 16 + lg * 4 + r;
                const int col = cb + nb * 16 + lr;
                if (EPI == 5) {
                    const int bb = row >> 11, sl = row & (SEQ - 1);
                    if (col < 1024) {        // Q: row-major [MT][1024]
                        ((unsigned short*)Cp)[(size_t)row * 1024 + col] = f2bf_bits(v);
                    } else {                 // K: fragment-ordered Kf
                        const int hh = (col >> 6) & 15, d = col & 63;
                        const int ktf = sl >> 7, mbf = (sl & 127) >> 4, lrf = sl & 15;
                        const int ksf = d >> 5, lgf = (d & 31) >> 3, j2 = d & 7;
                        unsigned short* Kf = (unsigned short*)(uintptr_t)bias;
                        Kf[((((size_t)(bb * 16 + hh) * 16 + ktf) * 8 + mbf) * 2 + ksf) * 512
                           + (lgf * 16 + lrf) * 8 + j2] = f2bf_bits(v);
                    }
                    continue;
                }
                const size_t idx = (size_t)row * Nsz + col;
                if (EPI == 0) {
                    ((unsigned short*)Cp)[idx] = f2bf_bits(v * scale);
                } else if (EPI == 1) {
                    ((float*)Cp)[idx] = v + res[idx];
                } else if (EPI == 2) {
                    float xx = v + bias[col];
                    ((unsigned short*)Cp)[idx] =
                        f2bf_bits(0.5f * xx * (1.0f + erff(xx * 0.70710678118654752f)));
                } else if (EPI == 6) {
                    ((unsigned short*)Cp)[idx] = f2bf_bits(v + res[idx]);
                } else if (EPI == 7) {
                    const float rv = bf2f(((const unsigned short*)res)[idx]);
                    ((float*)Cp)[idx] = v + bias[col] + rv;
                } else {
                    ((float*)Cp)[idx] = v + bias[col] + res[idx];
                }
            }
}

// ---------------- GEMM: 8-phase 256x256 counted-vmcnt schedule -------------
// (XCD-chunked 1-D launch; FF1's proven-best structure)
template<int P>
DEV void phase8_mfma(const char* base, int wm, int lr, int lg,
                     const bf16x8 (&bfr)[2][4], f32x4 (&acc)[8][4]) {
    bf16x8 af[2][2];
    #pragma unroll
    for (int ks = 0; ks < 2; ++ks)
        #pragma unroll
        for (int m = 0; m < 2; ++m) {
            const int ra = wm * 128 + P * 32 + m * 16 + lr;
            af[ks][m] = *(const bf16x8*)(base + (ra * 8 + ((ks * 4 + lg) ^ (ra & 7))) * 16);
        }
    __builtin_amdgcn_s_barrier();
    __builtin_amdgcn_s_setprio(1);
    #pragma unroll
    for (int ks = 0; ks < 2; ++ks)
        #pragma unroll
        for (int m = 0; m < 2; ++m)
            #pragma unroll
            for (int nb = 0; nb < 4; ++nb)
                acc[P * 2 + m][nb] = __builtin_amdgcn_mfma_f32_16x16x32_bf16(
                    af[ks][m], bfr[ks][nb], acc[P * 2 + m][nb], 0, 0, 0);
    __builtin_amdgcn_s_setprio(0);
}

template<int EPI>
__global__ __launch_bounds__(512, 2) void gemm_8ph(
    const unsigned short* __restrict__ A, const unsigned short* __restrict__ BT,
    void* __restrict__ Cp, const float* __restrict__ bias,
    const float* __restrict__ res, int Nsz, int Ksz, float scale)
{
    __shared__ alignas(16) unsigned short lds[2][32768];  // 2 x 64KB
    const int t = threadIdx.x, l = t & 63, w = t >> 6;
    const int wm = w >> 2, wn = w & 3;
    const int lr = l & 15, lg = l >> 4;
    // XCD-chunked swizzle for the 16x16 grid (1-D launch, 256 blocks)
    const int i = blockIdx.x;
    const int xcd = i & 7, s = i >> 3;         // s 0..31
    const int c = xcd + 8 * (s >> 4);          // chunk 0..15 (4x4 chunk grid)
    const int j = s & 15;
    const int bm = (c & 3) * 4 + (j & 3);
    const int bn = (c >> 2) * 4 + (j >> 2);

    f32x4 acc[8][4] = {};
    const int nk = Ksz / 64;

    const unsigned short* Ab = A + (size_t)(bm * 256) * Ksz;
    const unsigned short* Bb = BT + (size_t)(bn * 256) * Ksz;

    auto stage = [&](int tile, int region) {
        char* base = (char*)lds[tile & 1];
        const int k0 = tile * 64;
        #pragma unroll
        for (int jj = 0; jj < 2; ++jj) {
            const int ci = t + jj * 512;       // 0..1023
            const int rr = ci >> 3, cc = ci & 7;
            int row; const unsigned short* src; int dchunk;
            if (region == 0)      { row = rr;                          src = Bb; dchunk = 2048 + row * 8 + cc; }
            else if (region == 1) { row = 128 + rr;                    src = Bb; dchunk = 2048 + row * 8 + cc; }
            else if (region == 2) { row = (rr < 64 ? rr : rr + 64);    src = Ab; dchunk = row * 8 + cc; }
            else                  { row = 64 + (rr < 64 ? rr : rr + 64); src = Ab; dchunk = row * 8 + cc; }
            gload16(src + (size_t)row * Ksz + k0 + ((cc ^ (row & 7)) << 3),
                    base + dchunk * 16);
        }
    };

    stage(0, 0); stage(0, 1); stage(0, 2); stage(0, 3);
    stage(1, 0); stage(1, 1); stage(1, 2);
    asm volatile("s_waitcnt vmcnt(6)" ::: "memory");
    __builtin_amdgcn_s_barrier();
    __builtin_amdgcn_sched_barrier(0);

    bf16x8 bfr[2][4];
    for (int kt = 0; kt < nk; ++kt) {
        const char* base = (const char*)lds[kt & 1];
        if (kt + 1 < nk) stage(kt + 1, 3);
        #pragma unroll
        for (int ks = 0; ks < 2; ++ks)
            #pragma unroll
            for (int nb = 0; nb < 4; ++nb) {
                const int rb_ = wn * 64 + nb * 16 + lr;
                bfr[ks][nb] = *(const bf16x8*)(base
                    + (2048 + rb_ * 8 + ((ks * 4 + lg) ^ (rb_ & 7))) * 16);
            }
        phase8_mfma<0>(base, wm, lr, lg, bfr, acc);
        __builtin_amdgcn_s_barrier();
        if (kt + 2 < nk) stage(kt + 2, 0);
        phase8_mfma<1>(base, wm, lr, lg, bfr, acc);
        __builtin_amdgcn_s_barrier();
        if (kt + 2 < nk) stage(kt + 2, 1);
        phase8_mfma<2>(base, wm, lr, lg, bfr, acc);
        __builtin_amdgcn_s_barrier();
        if (kt + 2 < nk) stage(kt + 2, 2);
        phase8_mfma<3>(base, wm, lr, lg, bfr, acc);
        if (kt + 2 < nk) asm volatile("s_waitcnt vmcnt(6)" ::: "memory");
        else             asm volatile("s_waitcnt vmcnt(0)" ::: "memory");
        __builtin_amdgcn_s_barrier();
        __builtin_amdgcn_sched_barrier(0);
    }

    const int rb = bm * 256 + wm * 128, cb = bn * 256 + wn * 64;
    #pragma unroll
    for (int mb = 0; mb < 8; ++mb)
        #pragma unroll
        for (int nb = 0; nb < 4; ++nb)
            #pragma unroll
            for (int r = 0; r < 4; ++r) {
                float v = acc[mb][nb][r];
                const int row = rb + mb * 16 + lg * 4 + r;
                const int col = cb + nb * 16 + lr;
                const size_t idx = (size_t)row * Nsz + col;
                if (EPI == 2) {
                    // tanh-GELU in sigmoid form: x*sigmoid(1.59577x(1+0.044715x^2))
                    const float xx = v + bias[col];
                    const float tq = xx * xx;
                    const float u = xx * fmaf(tq, 0.044715f, 1.0f);
                    const float e = exp2f(u * -2.30220795f);
                    ((unsigned short*)Cp)[idx] =
                        f2bf_bits(xx * __builtin_amdgcn_rcpf(1.0f + e));
                } else if (EPI == 0) {
                    ((unsigned short*)Cp)[idx] = f2bf_bits(v * scale);
                } else {
                    ((float*)Cp)[idx] = v + bias[col] + res[idx];
                }
            }
}

// ---------------- causal flash attention (XCD-L2 swizzle + fast-exp2) ------
__global__ __launch_bounds__(512, 2) void attn_kernel(
    const unsigned short* __restrict__ Qg, const unsigned short* __restrict__ Kfg,
    const unsigned short* __restrict__ Vfg, unsigned short* __restrict__ Og)
{
    __shared__ alignas(16) unsigned short ldsK[2][128 * 64];
    __shared__ alignas(16) unsigned short ldsVT[2][64 * 128];
    const int t = threadIdx.x, l = t & 63, w = t >> 6;
    const int lr = l & 15, lg = l >> 4;
    const int i = blockIdx.x;
    const int qtA = (i >> 3) & 7, qtB = 15 - qtA;
    const int bh = (i & 7) + 8 * (i >> 6);
    const int b = bh >> 4, h = bh & 15;
    const unsigned short* Qbase = Qg + (size_t)b * SEQ * 1024 + h * 64;
    const unsigned short* Kbase = Kfg + (size_t)bh * 131072;
    const unsigned short* Vbase = Vfg + (size_t)bh * 131072;

    const int wq0A = qtA * 128 + w * 16, qrowA = wq0A + lr;
    const int wq0B = qtB * 128 + w * 16, qrowB = wq0B + lr;
    bf16x8 qfA[2], qfB[2];
    #pragma unroll
    for (int ks = 0; ks < 2; ++ks) {
        qfA[ks] = *(const bf16x8*)(Qbase + (size_t)qrowA * 1024 + ks * 32 + lg * 8);
        qfB[ks] = *(const bf16x8*)(Qbase + (size_t)qrowB * 1024 + ks * 32 + lg * 8);
    }

    f32x4 oaccA[4] = {}, oaccB[4] = {};
    f32x4 laccA = {}, laccB = {};
    bf16x8 onesv;
    #pragma unroll
    for (int i2 = 0; i2 < 8; ++i2) onesv[i2] = (__bf16)1.0f;

    const int lby = l * 16;  // lane byte offset for fragment reads
    const int nkt = qtB + 1;

    // prologue: stage tile 0 (pure linear copy)
    #pragma unroll
    for (int p = 0; p < 2; ++p) {
        const int ci = t + p * 512;
        gload16(Kbase + (size_t)ci * 8, (char*)ldsK[0] + ci * 16);
        gload16(Vbase + (size_t)ci * 8, (char*)ldsVT[0] + ci * 16);
    }
    asm volatile("s_waitcnt vmcnt(0)" ::: "memory");
    __builtin_amdgcn_s_barrier();

    for (int kt = 0; kt < nkt; ++kt) {
        const int cur = kt & 1;
        if (kt + 1 < nkt) {
            #pragma unroll
            for (int p = 0; p < 2; ++p) {
                const int ci = t + p * 512;
                gload16(Kbase + (size_t)((kt + 1) * 1024 + ci) * 8,
                        (char*)ldsK[cur ^ 1] + ci * 16);
                gload16(Vbase + (size_t)((kt + 1) * 1024 + ci) * 8,
                        (char*)ldsVT[cur ^ 1] + ci * 16);
            }
            asm volatile("s_waitcnt vmcnt(4)" ::: "memory");
        } else {
            asm volatile("s_waitcnt vmcnt(0)" ::: "memory");
        }
        __builtin_amdgcn_s_barrier();
        __builtin_amdgcn_sched_barrier(0);

        const char* lk = (const char*)ldsK[cur];
        const char* lv = (const char*)ldsVT[cur];
        const int kt0 = kt * 128;

        // mask + P = fast-exp2(st) directly in bf16 + pack
        auto run_softmax = [&](f32x4 (&st)[8], int qrow, bool diag, bf16x8 (&pa)[4]) {
            if (diag) {
                #pragma unroll
                for (int mb = 0; mb < 8; ++mb)
                    #pragma unroll
                    for (int r = 0; r < 4; ++r)
                        if (kt0 + mb * 16 + lg * 4 + r > qrow) st[mb][r] = -1e30f;
            }
            union { bf16x8 v; unsigned short u[8]; } pk[4];
            #pragma unroll
            for (int ks = 0; ks < 4; ++ks)
                #pragma unroll
                for (int jj = 0; jj < 4; ++jj) {
                    pk[ks].u[jj]     = fast_exp2_bf(st[2 * ks][jj]);
                    pk[ks].u[jj + 4] = fast_exp2_bf(st[2 * ks + 1][jj]);
                }
            #pragma unroll
            for (int ks = 0; ks < 4; ++ks) pa[ks] = pk[ks].v;
        };

        auto iter_body = [&](auto DOA) {
            constexpr bool doA = DOA.value;
            f32x4 stA[8], stB[8];
            #pragma unroll
            for (int mb = 0; mb < 8; ++mb)
                #pragma unroll
                for (int r = 0; r < 4; ++r) { stA[mb][r] = -SM_SHIFT; stB[mb][r] = -SM_SHIFT; }
            // QK off one K-frag read: chunk (mb*2+ks)*64 + lane (const offsets)
            __builtin_amdgcn_s_setprio(1);
            #pragma unroll
            for (int ks = 0; ks < 2; ++ks)
                #pragma unroll
                for (int mb = 0; mb < 8; ++mb) {
                    bf16x8 kf = *(const bf16x8*)(lk + (mb * 2 + ks) * 1024 + lby);
                    if constexpr (doA)
                        stA[mb] = __builtin_amdgcn_mfma_f32_16x16x32_bf16(kf, qfA[ks], stA[mb], 0, 0, 0);
                    stB[mb] = __builtin_amdgcn_mfma_f32_16x16x32_bf16(kf, qfB[ks], stB[mb], 0, 0, 0);
                }
            __builtin_amdgcn_s_setprio(0);

            bf16x8 paA[4], paB[4];
            if constexpr (doA)
                run_softmax(stA, qrowA, kt == qtA, paA);
            run_softmax(stB, qrowB, kt == qtB, paB);

            // PV off one V-frag read: chunk (ks*4+nb)*64 + lane
            __builtin_amdgcn_s_setprio(1);
            #pragma unroll
            for (int ks = 0; ks < 4; ++ks) {
                #pragma unroll
                for (int nb = 0; nb < 4; ++nb) {
                    bf16x8 vbv = *(const bf16x8*)(lv + (ks * 4 + nb) * 1024 + lby);
                    if constexpr (doA)
                        oaccA[nb] = __builtin_amdgcn_mfma_f32_16x16x32_bf16(paA[ks], vbv, oaccA[nb], 0, 0, 0);
                    oaccB[nb] = __builtin_amdgcn_mfma_f32_16x16x32_bf16(paB[ks], vbv, oaccB[nb], 0, 0, 0);
                }
                if constexpr (doA)
                    laccA = __builtin_amdgcn_mfma_f32_16x16x32_bf16(paA[ks], onesv, laccA, 0, 0, 0);
                laccB = __builtin_amdgcn_mfma_f32_16x16x32_bf16(paB[ks], onesv, laccB, 0, 0, 0);
            }
            __builtin_amdgcn_s_setprio(0);
        };

        if (kt <= qtA) iter_body(TrueC{}); else iter_body(FalseC{});

        __builtin_amdgcn_s_barrier();
    }

    unsigned short* Obase = Og + (size_t)b * SEQ * DM + h * 64;
    #pragma unroll
    for (int j = 0; j < 4; ++j) {
        const float invA = 1.0f / laccA[j];
        const float invB = 1.0f / laccB[j];
        const int rowA = wq0A + lg * 4 + j;
        const int rowB = wq0B + lg * 4 + j;
        #pragma unroll
        for (int nb = 0; nb < 4; ++nb) {
            Obase[(size_t)rowA * DM + nb * 16 + lr] = f2bf_bits(oaccA[nb][j] * invA);
            Obase[(size_t)rowB * DM + nb * 16 + lr] = f2bf_bits(oaccB[nb][j] * invB);
        }
    }
}

// ---------------- launcher ----------------
extern "C" void kernel_launch(void* const* d_in, const int* in_sizes, int n_in,
                              void* d_out, int out_size, void* d_ws, size_t ws_size,
                              hipStream_t stream) {
    (void)in_sizes; (void)n_in; (void)out_size; (void)ws_size;
    const float* x    = (const float*)d_in[0];
    const float* Wq   = (const float*)d_in[1];
    const float* Wk   = (const float*)d_in[2];
    const float* Wv   = (const float*)d_in[3];
    const float* Wo   = (const float*)d_in[4];
    const float* ln1g = (const float*)d_in[5];
    const float* ln1b = (const float*)d_in[6];
    const float* ln2g = (const float*)d_in[7];
    const float* ln2b = (const float*)d_in[8];
    const float* W1   = (const float*)d_in[9];
    const float* b1   = (const float*)d_in[10];
    const float* W2   = (const float*)d_in[11];
    const float* b2   = (const float*)d_in[12];
    float* out = (float*)d_out;

    char* ws = (char*)d_ws;
    const size_t MB = 1ull << 20;
    unsigned short* xn1   = (unsigned short*)(ws + 0 * MB);   // 8 MB [4096][1024]
    unsigned short* Qb    = (unsigned short*)(ws + 8 * MB);   // 8 MB [4096][1024]
    unsigned short* Kf    = (unsigned short*)(ws + 16 * MB);  // 8 MB fragment-ordered
    unsigned short* Vf    = (unsigned short*)(ws + 24 * MB);  // 8 MB fragment-ordered
    unsigned short* ffa   = (unsigned short*)(ws + 0 * MB);   // 32 MB (aliases the above)
    unsigned short* attno = (unsigned short*)(ws + 32 * MB);  // 8 MB
    unsigned short* x2b   = (unsigned short*)(ws + 40 * MB);  // 8 MB bf16 residual
    unsigned short* h2    = (unsigned short*)(ws + 56 * MB);  // 8 MB
    unsigned short* WqkT  = (unsigned short*)(ws + 64 * MB);  // 4 MB [2048][1024]
    unsigned short* WvT   = (unsigned short*)(ws + 68 * MB);  // 2 MB
    unsigned short* WoT   = (unsigned short*)(ws + 70 * MB);  // 2 MB
    unsigned short* W1T   = (unsigned short*)(ws + 72 * MB);  // 8 MB
    unsigned short* W2T   = (unsigned short*)(ws + 80 * MB);  // 8 MB  (total 88 MB)

    dim3 blk(256);
    // ALL input-only prep (six weight transposes + LN1) in ONE launch
    prep_all<<<dim3(3072 + MT), blk, 0, stream>>>(Wq, Wk, Wv, Wo, W1, W2,
                                                  WqkT, WvT, WoT, W1T, W2T,
                                                  x, ln1g, ln1b, xn1);

    // fused Q|K projection (XCD-chunked swizzle): Q -> Qb, K -> Kf
    gemm_pipe<5, 128, 256, 2, 4, 1><<<dim3(256), dim3(512), 0, stream>>>(
        xn1, WqkT, Qb, (const float*)Kf, nullptr, 2048, DM, 1.0f);
    // V projection -> Vf fragment-ordered; XCD-chunked swizzle (SWZ=2)
    gemm_pipe<4, 128, 64, 4, 1, 2><<<dim3(512), blk, 0, stream>>>(
        xn1, WvT, Vf, nullptr, nullptr, DM, DM, 1.0f);

    attn_kernel<<<dim3(256), dim3(512), 0, stream>>>(Qb, Kf, Vf, attno);

    // Wo + residual -> bf16 x2b; XCD-chunked swizzle (SWZ=2)
    gemm_pipe<6, 128, 64, 4, 1, 2><<<dim3(512), blk, 0, stream>>>(
        attno, WoT, x2b, nullptr, x, DM, DM, 1.0f);

    ln_kernel_b<<<dim3(MT), blk, 0, stream>>>(x2b, ln2g, ln2b, h2);

    // FF1: 8-phase 256x256 schedule, XCD-chunked swizzle (1-D grid 256)
    gemm_8ph<2><<<dim3(256), dim3(512), 0, stream>>>(
        h2, W1T, ffa, b1, nullptr, DFF, DM, 1.0f);
    // FF2 + bias + bf16 residual -> f32 out; XCD-chunked swizzle (SWZ=2)
    gemm_pipe<7, 128, 64, 4, 1, 2><<<dim3(512), blk, 0, stream>>>(
        ffa, W2T, out, b2, (const float*)x2b, DM, DFF, 1.0f);
}